// Round 3
// baseline (577.924 us; speedup 1.0000x reference)
//
#include <hip/hip_runtime.h>
#include <cmath>

typedef _Float16 f16;
typedef _Float16 f16x8 __attribute__((ext_vector_type(8)));
typedef float f32x4 __attribute__((ext_vector_type(4)));
typedef unsigned long long u64;

#define M_OUT 2049          // N//2 + 1
#define NDIM 4096
#define MPAD 2112           // 2049 padded to 64-multiple (33 tiles)
// reference: -2.0 * 3.14 / N computed in f64, rounded once to f32
#define CW ((float)(-2.0 * 3.14 / 4096.0))

// ws layout:
//   [0, 16384)             row means (4096 f32)
//   [16384, 16384+2049*8)  argmax cells (u64, packed (amp2_bits<<32)|~col)
//   [40960, ...)           tables (layout depends on path)
// FULL path (chunk-major):
//   A tables: Ach,Acl,Ash,Asl each [512][2112][8] f16   (4 x 17.3 MB)
//   X tables: Xh,Xl           each [512][4096][8] f16   (2 x 33.6 MB)
// MID path (row-major): Ach,Acl,Ash,Asl each [2112][4096] f16
static const size_t WS_MEAN  = 0;
static const size_t WS_CELLS = 16384;
static const size_t WS_TBL   = 40960;
static const size_t A_ELEMS  = (size_t)MPAD * NDIM;        // 8650752
static const size_t X_ELEMS  = (size_t)NDIM * NDIM;        // 16777216
static const size_t WS_XTBL  = WS_TBL + 4 * A_ELEMS * sizeof(f16);
static const size_t WS_FULL_END = WS_XTBL + 2 * X_ELEMS * sizeof(f16);
static const size_t WS_MID_END  = WS_TBL + 4 * A_ELEMS * sizeof(f16);

#define AS1 __attribute__((address_space(1)))
#define AS3 __attribute__((address_space(3)))
__device__ __forceinline__ void async_copy16(const void* gsrc, void* ldst) {
    __builtin_amdgcn_global_load_lds((const AS1 unsigned int*)gsrc,
                                     (AS3 unsigned int*)ldst, 16, 0, 0);
}

__device__ __forceinline__ void split_f16(float v, f16& hi, f16& lo) {
    hi = (f16)v;
    lo = (f16)((v - (float)hi) * 64.0f);
}

// ---------------- row means ----------------
__global__ void mean_kernel(const float* __restrict__ x, float* __restrict__ meanv) {
    const int row = blockIdx.x;
    const float4* xr = (const float4*)(x + (size_t)row * NDIM);
    float s = 0.f;
    for (int i = threadIdx.x; i < NDIM / 4; i += 256) {
        float4 v = xr[i];
        s += (v.x + v.y) + (v.z + v.w);
    }
    for (int off = 32; off; off >>= 1) s += __shfl_down(s, off);
    __shared__ float ps[4];
    if ((threadIdx.x & 63) == 0) ps[threadIdx.x >> 6] = s;
    __syncthreads();
    if (threadIdx.x == 0) {
        float t = (ps[0] + ps[1]) + (ps[2] + ps[3]);
        meanv[row] = t * (1.0f / 4096.0f);
    }
}

// ---------------- init argmax cells ----------------
__global__ void init_cells(u64* __restrict__ cells) {
    int i = blockIdx.x * 256 + threadIdx.x;
    if (i < M_OUT) cells[i] = 0ull;
}

// ================= FULL path: chunk-major tables =================
__global__ void fill_A_cm(f16* __restrict__ tbl) {
    const int c = blockIdx.x;                      // k-chunk 0..511
    const int m = blockIdx.y * 256 + threadIdx.x;  // 0..2303
    if (m >= MPAD) return;
    const bool valid = (m < M_OUT);
    f16x8 chv, clv, shv, slv;
    for (int j = 0; j < 8; ++j) {
        float cc = 0.f, ss = 0.f;
        if (valid) {
            int kk = c * 8 + j;
            float ang = CW * (float)(m * kk);      // m*kk < 2^24 -> exact
            sincosf(ang, &ss, &cc);
        }
        f16 h, l;
        split_f16(cc, h, l); chv[j] = h; clv[j] = l;
        split_f16(ss, h, l); shv[j] = h; slv[j] = l;
    }
    size_t idx = ((size_t)c * MPAD + m) * 8;
    *(f16x8*)(tbl + idx)                 = chv;
    *(f16x8*)(tbl + A_ELEMS + idx)       = clv;
    *(f16x8*)(tbl + 2 * A_ELEMS + idx)   = shv;
    *(f16x8*)(tbl + 3 * A_ELEMS + idx)   = slv;
}

__global__ void fill_X_cm(const float* __restrict__ x, const float* __restrict__ meanv,
                          f16* __restrict__ xtbl) {
    const int c = blockIdx.x;                      // k-chunk 0..511
    const int n = blockIdx.y * 256 + threadIdx.x;  // 0..4095
    f16x8 hv, lv;
    for (int j = 0; j < 8; ++j) {
        int k = c * 8 + j;
        float v = x[(size_t)k * NDIM + n] - meanv[k];
        f16 h, l;
        split_f16(v, h, l);
        hv[j] = h; lv[j] = l;
    }
    size_t idx = ((size_t)c * NDIM + n) * 8;
    *(f16x8*)(xtbl + idx)           = hv;
    *(f16x8*)(xtbl + X_ELEMS + idx) = lv;
}

// Fused split-f16 DFT GEMM + argmax.
// A fragments: direct global->VGPR (contiguous 16B in chunk-major layout),
// software-pipelined one K-iter ahead. X: global_load_lds staging.
// Tile: BM=64 x BN=128 x BK=32. 256 threads = 4 waves (2x2 of 32x64).
__global__ __launch_bounds__(256, 2) void dft_gemm_cm(
    const f16* __restrict__ atbl, const f16* __restrict__ xtbl,
    u64* __restrict__ cells)
{
    __shared__ alignas(16) f16 sX[2][4][128][8];   // 16 KB

    const int t = threadIdx.x;
    const int n0      = blockIdx.x * 128;
    const int rowBase = blockIdx.y * 64;

    const int lane = t & 63;
    const int w  = t >> 6;
    const int wm = w >> 1, wn = w & 1;
    const int q  = lane >> 4, ln = lane & 15;

    f32x4 aC0[2][4], aC1[2][4], aS0[2][4], aS1[2][4];
#pragma unroll
    for (int i = 0; i < 2; ++i)
#pragma unroll
        for (int j = 0; j < 4; ++j) {
            aC0[i][j] = (f32x4){0.f, 0.f, 0.f, 0.f};
            aC1[i][j] = (f32x4){0.f, 0.f, 0.f, 0.f};
            aS0[i][j] = (f32x4){0.f, 0.f, 0.f, 0.f};
            aS1[i][j] = (f32x4){0.f, 0.f, 0.f, 0.f};
        }

    // A-fragment global base: row = rowBase + wm*32 + tm*16 + ln, chunk = kc + q
    const f16* aBase = atbl + ((size_t)q * MPAD + (rowBase + wm * 32 + ln)) * 8;

    // X staging: 4 async ops per wave cover [2 tables][4 planes][2 halves]
    const int xq0 = w >> 1, xh = w & 1;
    const int xq1 = xq0 + 2;
    const f16* xG0 = xtbl + ((size_t)xq0 * NDIM + n0 + xh * 64 + lane) * 8;
    const f16* xG1 = xtbl + ((size_t)xq1 * NDIM + n0 + xh * 64 + lane) * 8;
    const f16* xG2 = xG0 + X_ELEMS;
    const f16* xG3 = xG1 + X_ELEMS;

    auto loadA = [&](f16x8 (&dst)[2][4], int kc) {
#pragma unroll
        for (int tm = 0; tm < 2; ++tm)
#pragma unroll
            for (int tb = 0; tb < 4; ++tb)
                dst[tm][tb] = *(const f16x8*)(aBase + (size_t)tb * A_ELEMS
                              + ((size_t)kc * MPAD + tm * 16) * 8);
    };

    auto stageX = [&](int kc) {
        const size_t kadv = (size_t)kc * NDIM * 8;
        async_copy16(xG0 + kadv, &sX[0][xq0][xh * 64][0]);
        async_copy16(xG1 + kadv, &sX[0][xq1][xh * 64][0]);
        async_copy16(xG2 + kadv, &sX[1][xq0][xh * 64][0]);
        async_copy16(xG3 + kadv, &sX[1][xq1][xh * 64][0]);
    };

    auto compute = [&](f16x8 (&A)[2][4]) {
        f16x8 bh[4], bl[4];
#pragma unroll
        for (int tn = 0; tn < 4; ++tn) {
            int nl = wn * 64 + tn * 16 + ln;
            bh[tn] = *(const f16x8*)&sX[0][q][nl][0];
            bl[tn] = *(const f16x8*)&sX[1][q][nl][0];
        }
#pragma unroll
        for (int tm = 0; tm < 2; ++tm)
#pragma unroll
            for (int tn = 0; tn < 4; ++tn) {
                aC0[tm][tn] = __builtin_amdgcn_mfma_f32_16x16x32_f16(A[tm][0], bh[tn], aC0[tm][tn], 0, 0, 0);
                aC1[tm][tn] = __builtin_amdgcn_mfma_f32_16x16x32_f16(A[tm][0], bl[tn], aC1[tm][tn], 0, 0, 0);
                aC1[tm][tn] = __builtin_amdgcn_mfma_f32_16x16x32_f16(A[tm][1], bh[tn], aC1[tm][tn], 0, 0, 0);
                aS0[tm][tn] = __builtin_amdgcn_mfma_f32_16x16x32_f16(A[tm][2], bh[tn], aS0[tm][tn], 0, 0, 0);
                aS1[tm][tn] = __builtin_amdgcn_mfma_f32_16x16x32_f16(A[tm][2], bl[tn], aS1[tm][tn], 0, 0, 0);
                aS1[tm][tn] = __builtin_amdgcn_mfma_f32_16x16x32_f16(A[tm][3], bh[tn], aS1[tm][tn], 0, 0, 0);
            }
    };

    f16x8 Aa[2][4], Ab[2][4];
    loadA(Aa, 0);
    for (int kc = 0; kc < 512; kc += 8) {
        __syncthreads();
        loadA(Ab, kc + 4);            // prefetch next half-iter's A (overlaps X DMA)
        stageX(kc);
        __syncthreads();
        compute(Aa);
        __syncthreads();
        if (kc + 8 < 512) loadA(Aa, kc + 8);
        stageX(kc + 4);
        __syncthreads();
        compute(Ab);
    }

    // ---- epilogue: amp^2, per-row argmax, atomicMax into cells ----
    const float inv64 = 0.015625f;
#pragma unroll
    for (int tm = 0; tm < 2; ++tm) {
#pragma unroll
        for (int r = 0; r < 4; ++r) {
            u64 best = 0ull;
#pragma unroll
            for (int tn = 0; tn < 4; ++tn) {
                float C = aC0[tm][tn][r] + aC1[tm][tn][r] * inv64;
                float S = aS0[tm][tn][r] + aS1[tm][tn][r] * inv64;
                float a2 = C * C + S * S;
                int col = n0 + wn * 64 + tn * 16 + ln;
                u64 key = ((u64)__float_as_uint(a2) << 32) | (unsigned)(~col);
                if (key > best) best = key;
            }
            for (int off = 1; off < 16; off <<= 1) {
                unsigned hi = (unsigned)(best >> 32), lo = (unsigned)best;
                unsigned ho = __shfl_xor(hi, off);
                unsigned lo2 = __shfl_xor(lo, off);
                u64 o = ((u64)ho << 32) | lo2;
                if (o > best) best = o;
            }
            if (ln == 0) {
                int grow = rowBase + wm * 32 + tm * 16 + q * 4 + r;
                if (grow < M_OUT) atomicMax(cells + grow, best);
            }
        }
    }
}

// ================= MID/LOW fallback path =================
__global__ void fill_tables_rm(f16* __restrict__ tbl) {
    long long g = (long long)blockIdx.x * 256 + threadIdx.x;
    if (g >= (long long)(MPAD * 512)) return;
    int m  = (int)(g >> 9);
    int kq = ((int)g & 511) * 8;
    bool valid = (m < M_OUT);
    f16x8 chv, clv, shv, slv;
    for (int j = 0; j < 8; ++j) {
        float c = 0.f, s = 0.f;
        if (valid) {
            int kk = kq + j;
            float ang = CW * (float)(m * kk);
            sincosf(ang, &s, &c);
        }
        f16 h, l;
        split_f16(c, h, l); chv[j] = h; clv[j] = l;
        split_f16(s, h, l); shv[j] = h; slv[j] = l;
    }
    size_t idx = (size_t)m * NDIM + kq;
    *(f16x8*)(tbl + idx)               = chv;
    *(f16x8*)(tbl + A_ELEMS + idx)     = clv;
    *(f16x8*)(tbl + 2 * A_ELEMS + idx) = shv;
    *(f16x8*)(tbl + 3 * A_ELEMS + idx) = slv;
}

#define PK 40   // padded k-stride: all 8 bank groups covered -> 2-way (free)
__global__ __launch_bounds__(256, 2) void dft_gemm_fb(
    const float* __restrict__ x, const float* __restrict__ meanv,
    const f16* __restrict__ tbl, int useTbl,
    u64* __restrict__ cells)
{
    __shared__ alignas(16) f16 Ach[64][PK];
    __shared__ alignas(16) f16 Acl[64][PK];
    __shared__ alignas(16) f16 Ash[64][PK];
    __shared__ alignas(16) f16 Asl[64][PK];
    __shared__ alignas(16) f16 Xh[128][PK];
    __shared__ alignas(16) f16 Xl[128][PK];

    const int t = threadIdx.x;
    const int n0      = blockIdx.x * 128;
    const int rowBase = blockIdx.y * 64;

    const int am  = t >> 2;
    const int akq = (t & 3) * 8;
    const int xn  = t & 127;
    const int xkh = (t >> 7) * 16;

    const int lane = t & 63;
    const int w  = t >> 6;
    const int wm = w >> 1, wn = w & 1;
    const int q  = lane >> 4, ln = lane & 15;

    f32x4 aC0[2][4], aC1[2][4], aS0[2][4], aS1[2][4];
    for (int i = 0; i < 2; ++i)
        for (int j = 0; j < 4; ++j) {
            aC0[i][j] = (f32x4){0.f, 0.f, 0.f, 0.f};
            aC1[i][j] = (f32x4){0.f, 0.f, 0.f, 0.f};
            aS0[i][j] = (f32x4){0.f, 0.f, 0.f, 0.f};
            aS1[i][j] = (f32x4){0.f, 0.f, 0.f, 0.f};
        }

    const int arow = rowBase + am;
    const bool avalid = (arow < M_OUT);

    for (int k0 = 0; k0 < NDIM; k0 += 32) {
        __syncthreads();
        if (useTbl) {
            size_t idx = (size_t)arow * NDIM + k0 + akq;
            *(f16x8*)&Ach[am][akq] = *(const f16x8*)(tbl + idx);
            *(f16x8*)&Acl[am][akq] = *(const f16x8*)(tbl + A_ELEMS + idx);
            *(f16x8*)&Ash[am][akq] = *(const f16x8*)(tbl + 2 * A_ELEMS + idx);
            *(f16x8*)&Asl[am][akq] = *(const f16x8*)(tbl + 3 * A_ELEMS + idx);
        } else {
            f16x8 chv, clv, shv, slv;
            for (int j = 0; j < 8; ++j) {
                float c = 0.f, s = 0.f;
                if (avalid) {
                    int kk = k0 + akq + j;
                    float ang = CW * (float)(arow * kk);
                    sincosf(ang, &s, &c);
                }
                f16 h, l;
                split_f16(c, h, l); chv[j] = h; clv[j] = l;
                split_f16(s, h, l); shv[j] = h; slv[j] = l;
            }
            *(f16x8*)&Ach[am][akq] = chv;
            *(f16x8*)&Acl[am][akq] = clv;
            *(f16x8*)&Ash[am][akq] = shv;
            *(f16x8*)&Asl[am][akq] = slv;
        }
        {
            const float* xp = x + (size_t)(k0 + xkh) * NDIM + n0 + xn;
            f16x8 h0, h1, l0, l1;
            for (int r = 0; r < 16; ++r) {
                float v = xp[(size_t)r * NDIM] - meanv[k0 + xkh + r];
                f16 hi, lo;
                split_f16(v, hi, lo);
                if (r < 8) { h0[r] = hi; l0[r] = lo; }
                else       { h1[r - 8] = hi; l1[r - 8] = lo; }
            }
            *(f16x8*)&Xh[xn][xkh]     = h0;
            *(f16x8*)&Xh[xn][xkh + 8] = h1;
            *(f16x8*)&Xl[xn][xkh]     = l0;
            *(f16x8*)&Xl[xn][xkh + 8] = l1;
        }
        __syncthreads();
        f16x8 fch[2], fcl[2], fsh[2], fsl[2], bh[4], bl[4];
        for (int tm = 0; tm < 2; ++tm) {
            int ml = wm * 32 + tm * 16 + ln;
            fch[tm] = *(const f16x8*)&Ach[ml][q * 8];
            fcl[tm] = *(const f16x8*)&Acl[ml][q * 8];
            fsh[tm] = *(const f16x8*)&Ash[ml][q * 8];
            fsl[tm] = *(const f16x8*)&Asl[ml][q * 8];
        }
        for (int tn = 0; tn < 4; ++tn) {
            int nl = wn * 64 + tn * 16 + ln;
            bh[tn] = *(const f16x8*)&Xh[nl][q * 8];
            bl[tn] = *(const f16x8*)&Xl[nl][q * 8];
        }
        for (int tm = 0; tm < 2; ++tm)
            for (int tn = 0; tn < 4; ++tn) {
                aC0[tm][tn] = __builtin_amdgcn_mfma_f32_16x16x32_f16(fch[tm], bh[tn], aC0[tm][tn], 0, 0, 0);
                aC1[tm][tn] = __builtin_amdgcn_mfma_f32_16x16x32_f16(fch[tm], bl[tn], aC1[tm][tn], 0, 0, 0);
                aC1[tm][tn] = __builtin_amdgcn_mfma_f32_16x16x32_f16(fcl[tm], bh[tn], aC1[tm][tn], 0, 0, 0);
                aS0[tm][tn] = __builtin_amdgcn_mfma_f32_16x16x32_f16(fsh[tm], bh[tn], aS0[tm][tn], 0, 0, 0);
                aS1[tm][tn] = __builtin_amdgcn_mfma_f32_16x16x32_f16(fsh[tm], bl[tn], aS1[tm][tn], 0, 0, 0);
                aS1[tm][tn] = __builtin_amdgcn_mfma_f32_16x16x32_f16(fsl[tm], bh[tn], aS1[tm][tn], 0, 0, 0);
            }
    }

    const float inv64 = 0.015625f;
    for (int tm = 0; tm < 2; ++tm) {
        for (int r = 0; r < 4; ++r) {
            u64 best = 0ull;
            for (int tn = 0; tn < 4; ++tn) {
                float C = aC0[tm][tn][r] + aC1[tm][tn][r] * inv64;
                float S = aS0[tm][tn][r] + aS1[tm][tn][r] * inv64;
                float a2 = C * C + S * S;
                int col = n0 + wn * 64 + tn * 16 + ln;
                u64 key = ((u64)__float_as_uint(a2) << 32) | (unsigned)(~col);
                if (key > best) best = key;
            }
            for (int off = 1; off < 16; off <<= 1) {
                unsigned hi = (unsigned)(best >> 32), lo = (unsigned)best;
                unsigned ho = __shfl_xor(hi, off);
                unsigned lo2 = __shfl_xor(lo, off);
                u64 o = ((u64)ho << 32) | lo2;
                if (o > best) best = o;
            }
            if (ln == 0) {
                int grow = rowBase + wm * 32 + tm * 16 + q * 4 + r;
                if (grow < M_OUT) atomicMax(cells + grow, best);
            }
        }
    }
}

// ---------------- cells -> output ----------------
__global__ void out_kernel(const u64* __restrict__ cells, float* __restrict__ out) {
    int i = blockIdx.x * 256 + threadIdx.x;
    if (i < M_OUT) {
        unsigned col = ~(unsigned)(cells[i] & 0xFFFFFFFFull);
        float freq = (float)col / (4096.0f / 30.0f);
        out[i] = freq * 60.0f;
    }
}

extern "C" void kernel_launch(void* const* d_in, const int* in_sizes, int n_in,
                              void* d_out, int out_size, void* d_ws, size_t ws_size,
                              hipStream_t stream) {
    const float* x = (const float*)d_in[0];
    char* ws = (char*)d_ws;
    float* meanv = (float*)(ws + WS_MEAN);
    u64*   cells = (u64*)(ws + WS_CELLS);
    f16*   atbl  = (f16*)(ws + WS_TBL);
    f16*   xtbl  = (f16*)(ws + WS_XTBL);
    float* out   = (float*)d_out;

    hipLaunchKernelGGL(init_cells, dim3((M_OUT + 255) / 256), dim3(256), 0, stream, cells);
    hipLaunchKernelGGL(mean_kernel, dim3(NDIM), dim3(256), 0, stream, x, meanv);

    if (ws_size >= WS_FULL_END) {
        hipLaunchKernelGGL(fill_A_cm, dim3(512, 9), dim3(256), 0, stream, atbl);
        hipLaunchKernelGGL(fill_X_cm, dim3(512, 16), dim3(256), 0, stream, x, meanv, xtbl);
        hipLaunchKernelGGL(dft_gemm_cm, dim3(32, 33), dim3(256), 0, stream, atbl, xtbl, cells);
    } else if (ws_size >= WS_MID_END) {
        hipLaunchKernelGGL(fill_tables_rm, dim3(4224), dim3(256), 0, stream, atbl);
        hipLaunchKernelGGL(dft_gemm_fb, dim3(32, 33), dim3(256), 0, stream,
                           x, meanv, atbl, 1, cells);
    } else {
        hipLaunchKernelGGL(dft_gemm_fb, dim3(32, 33), dim3(256), 0, stream,
                           x, meanv, atbl, 0, cells);
    }
    hipLaunchKernelGGL(out_kernel, dim3((M_OUT + 255) / 256), dim3(256), 0, stream, cells, out);
}

// Round 4
// 524.252 us; speedup vs baseline: 1.1024x; 1.1024x over previous
//
#include <hip/hip_runtime.h>
#include <cmath>

typedef _Float16 f16;
typedef _Float16 f16x8 __attribute__((ext_vector_type(8)));
typedef float f32x4 __attribute__((ext_vector_type(4)));
typedef unsigned long long u64;

#define M_OUT 2049          // N//2 + 1
#define NDIM 4096
#define MPAD 2112           // 2049 padded to 64-multiple (33 tiles)
// reference: -2.0 * 3.14 / N computed in f64, rounded once to f32
#define CW ((float)(-2.0 * 3.14 / 4096.0))

// ws layout:
//   [0, 16384)             row means (4096 f32)
//   [16384, 16384+2049*8)  argmax cells (u64, packed (amp2_bits<<32)|~col)
//   [40960, ...)           tables (layout depends on path)
// FULL path (chunk-major):
//   A tables: Ach,Acl,Ash,Asl each [512][2112][8] f16   (4 x 17.3 MB)
//   X tables: Xh,Xl           each [512][4096][8] f16   (2 x 33.6 MB)
// MID path (row-major): Ach,Acl,Ash,Asl each [2112][4096] f16
static const size_t WS_MEAN  = 0;
static const size_t WS_CELLS = 16384;
static const size_t WS_TBL   = 40960;
static const size_t A_ELEMS  = (size_t)MPAD * NDIM;        // 8650752
static const size_t X_ELEMS  = (size_t)NDIM * NDIM;        // 16777216
static const size_t WS_XTBL  = WS_TBL + 4 * A_ELEMS * sizeof(f16);
static const size_t WS_FULL_END = WS_XTBL + 2 * X_ELEMS * sizeof(f16);
static const size_t WS_MID_END  = WS_TBL + 4 * A_ELEMS * sizeof(f16);

#define AS1 __attribute__((address_space(1)))
#define AS3 __attribute__((address_space(3)))
__device__ __forceinline__ void async_copy16(const void* gsrc, void* ldst) {
    __builtin_amdgcn_global_load_lds((const AS1 unsigned int*)gsrc,
                                     (AS3 unsigned int*)ldst, 16, 0, 0);
}

__device__ __forceinline__ void split_f16(float v, f16& hi, f16& lo) {
    hi = (f16)v;
    lo = (f16)((v - (float)hi) * 64.0f);
}

// ---------------- row means ----------------
__global__ void mean_kernel(const float* __restrict__ x, float* __restrict__ meanv) {
    const int row = blockIdx.x;
    const float4* xr = (const float4*)(x + (size_t)row * NDIM);
    float s = 0.f;
    for (int i = threadIdx.x; i < NDIM / 4; i += 256) {
        float4 v = xr[i];
        s += (v.x + v.y) + (v.z + v.w);
    }
    for (int off = 32; off; off >>= 1) s += __shfl_down(s, off);
    __shared__ float ps[4];
    if ((threadIdx.x & 63) == 0) ps[threadIdx.x >> 6] = s;
    __syncthreads();
    if (threadIdx.x == 0) {
        float t = (ps[0] + ps[1]) + (ps[2] + ps[3]);
        meanv[row] = t * (1.0f / 4096.0f);
    }
}

// ---------------- init argmax cells ----------------
__global__ void init_cells(u64* __restrict__ cells) {
    int i = blockIdx.x * 256 + threadIdx.x;
    if (i < M_OUT) cells[i] = 0ull;
}

// ================= FULL path: chunk-major tables =================
__global__ void fill_A_cm(f16* __restrict__ tbl) {
    const int c = blockIdx.x;                      // k-chunk 0..511
    const int m = blockIdx.y * 256 + threadIdx.x;  // 0..2303
    if (m >= MPAD) return;
    const bool valid = (m < M_OUT);
    f16x8 chv, clv, shv, slv;
    for (int j = 0; j < 8; ++j) {
        float cc = 0.f, ss = 0.f;
        if (valid) {
            int kk = c * 8 + j;
            float ang = CW * (float)(m * kk);      // m*kk < 2^24 -> exact
            sincosf(ang, &ss, &cc);
        }
        f16 h, l;
        split_f16(cc, h, l); chv[j] = h; clv[j] = l;
        split_f16(ss, h, l); shv[j] = h; slv[j] = l;
    }
    size_t idx = ((size_t)c * MPAD + m) * 8;
    *(f16x8*)(tbl + idx)                 = chv;
    *(f16x8*)(tbl + A_ELEMS + idx)       = clv;
    *(f16x8*)(tbl + 2 * A_ELEMS + idx)   = shv;
    *(f16x8*)(tbl + 3 * A_ELEMS + idx)   = slv;
}

__global__ void fill_X_cm(const float* __restrict__ x, const float* __restrict__ meanv,
                          f16* __restrict__ xtbl) {
    const int c = blockIdx.x;                      // k-chunk 0..511
    const int n = blockIdx.y * 256 + threadIdx.x;  // 0..4095
    f16x8 hv, lv;
    for (int j = 0; j < 8; ++j) {
        int k = c * 8 + j;
        float v = x[(size_t)k * NDIM + n] - meanv[k];
        f16 h, l;
        split_f16(v, h, l);
        hv[j] = h; lv[j] = l;
    }
    size_t idx = ((size_t)c * NDIM + n) * 8;
    *(f16x8*)(xtbl + idx)           = hv;
    *(f16x8*)(xtbl + X_ELEMS + idx) = lv;
}

// Fused split-f16 DFT GEMM + argmax.
// A fragments: direct global->VGPR (contiguous 16B, chunk-major), prefetched.
// X: double-buffered LDS, global_load_lds issued AFTER the barrier so the DMA
// overlaps the 48-MFMA compute phase (single barrier per half-iter).
// Tile: BM=64 x BN=128 x BK=32. 256 threads = 4 waves (2x2 of 32x64).
__global__ __launch_bounds__(256, 2) void dft_gemm_cm(
    const f16* __restrict__ atbl, const f16* __restrict__ xtbl,
    u64* __restrict__ cells)
{
    __shared__ alignas(16) f16 sX[2][2][4][128][8];   // [buf][tbl][plane][n][8] = 32 KB

    const int t = threadIdx.x;
    const int n0      = blockIdx.x * 128;
    const int rowBase = blockIdx.y * 64;

    const int lane = t & 63;
    const int w  = t >> 6;
    const int wm = w >> 1, wn = w & 1;
    const int q  = lane >> 4, ln = lane & 15;

    f32x4 aC0[2][4], aC1[2][4], aS0[2][4], aS1[2][4];
#pragma unroll
    for (int i = 0; i < 2; ++i)
#pragma unroll
        for (int j = 0; j < 4; ++j) {
            aC0[i][j] = (f32x4){0.f, 0.f, 0.f, 0.f};
            aC1[i][j] = (f32x4){0.f, 0.f, 0.f, 0.f};
            aS0[i][j] = (f32x4){0.f, 0.f, 0.f, 0.f};
            aS1[i][j] = (f32x4){0.f, 0.f, 0.f, 0.f};
        }

    // A-fragment global base: row = rowBase + wm*32 + tm*16 + ln, chunk = kc + q
    const f16* aBase = atbl + ((size_t)q * MPAD + (rowBase + wm * 32 + ln)) * 8;

    // X staging: 4 async ops per wave cover [2 tables][4 planes][2 halves]
    const int xq0 = w >> 1, xh = w & 1;
    const int xq1 = xq0 + 2;
    const f16* xG0 = xtbl + ((size_t)xq0 * NDIM + n0 + xh * 64 + lane) * 8;
    const f16* xG1 = xtbl + ((size_t)xq1 * NDIM + n0 + xh * 64 + lane) * 8;
    const f16* xG2 = xG0 + X_ELEMS;
    const f16* xG3 = xG1 + X_ELEMS;

    auto loadA = [&](f16x8 (&dst)[2][4], int kc) {
#pragma unroll
        for (int tm = 0; tm < 2; ++tm)
#pragma unroll
            for (int tb = 0; tb < 4; ++tb)
                dst[tm][tb] = *(const f16x8*)(aBase + (size_t)tb * A_ELEMS
                              + ((size_t)kc * MPAD + tm * 16) * 8);
    };

    auto stageX = [&](int buf, int kc) {
        const size_t kadv = (size_t)kc * NDIM * 8;
        async_copy16(xG0 + kadv, &sX[buf][0][xq0][xh * 64][0]);
        async_copy16(xG1 + kadv, &sX[buf][0][xq1][xh * 64][0]);
        async_copy16(xG2 + kadv, &sX[buf][1][xq0][xh * 64][0]);
        async_copy16(xG3 + kadv, &sX[buf][1][xq1][xh * 64][0]);
    };

    auto compute = [&](f16x8 (&A)[2][4], int buf) {
        f16x8 bh[4], bl[4];
#pragma unroll
        for (int tn = 0; tn < 4; ++tn) {
            int nl = wn * 64 + tn * 16 + ln;
            bh[tn] = *(const f16x8*)&sX[buf][0][q][nl][0];
            bl[tn] = *(const f16x8*)&sX[buf][1][q][nl][0];
        }
#pragma unroll
        for (int tm = 0; tm < 2; ++tm)
#pragma unroll
            for (int tn = 0; tn < 4; ++tn) {
                aC0[tm][tn] = __builtin_amdgcn_mfma_f32_16x16x32_f16(A[tm][0], bh[tn], aC0[tm][tn], 0, 0, 0);
                aC1[tm][tn] = __builtin_amdgcn_mfma_f32_16x16x32_f16(A[tm][0], bl[tn], aC1[tm][tn], 0, 0, 0);
                aC1[tm][tn] = __builtin_amdgcn_mfma_f32_16x16x32_f16(A[tm][1], bh[tn], aC1[tm][tn], 0, 0, 0);
                aS0[tm][tn] = __builtin_amdgcn_mfma_f32_16x16x32_f16(A[tm][2], bh[tn], aS0[tm][tn], 0, 0, 0);
                aS1[tm][tn] = __builtin_amdgcn_mfma_f32_16x16x32_f16(A[tm][2], bl[tn], aS1[tm][tn], 0, 0, 0);
                aS1[tm][tn] = __builtin_amdgcn_mfma_f32_16x16x32_f16(A[tm][3], bh[tn], aS1[tm][tn], 0, 0, 0);
            }
    };

    f16x8 Aa[2][4], Ab[2][4];
    loadA(Aa, 0);
    stageX(0, 0);
    for (int kc = 0; kc < 512; kc += 8) {
        // half-iter 1: compute buf0 (kc), prefetch buf1 (kc+4) during compute
        __syncthreads();                   // drains DMA for buf0 (issued last half-iter)
        stageX(1, kc + 4);
        loadA(Ab, kc + 4);
        compute(Aa, 0);
        // half-iter 2: compute buf1 (kc+4), prefetch buf0 (kc+8)
        __syncthreads();                   // drains DMA for buf1
        if (kc + 8 < 512) {
            stageX(0, kc + 8);
            loadA(Aa, kc + 8);
        }
        compute(Ab, 1);
    }

    // ---- epilogue: amp^2, per-row argmax, atomicMax into cells ----
    const float inv64 = 0.015625f;
#pragma unroll
    for (int tm = 0; tm < 2; ++tm) {
#pragma unroll
        for (int r = 0; r < 4; ++r) {
            u64 best = 0ull;
#pragma unroll
            for (int tn = 0; tn < 4; ++tn) {
                float C = aC0[tm][tn][r] + aC1[tm][tn][r] * inv64;
                float S = aS0[tm][tn][r] + aS1[tm][tn][r] * inv64;
                float a2 = C * C + S * S;
                int col = n0 + wn * 64 + tn * 16 + ln;
                u64 key = ((u64)__float_as_uint(a2) << 32) | (unsigned)(~col);
                if (key > best) best = key;
            }
            for (int off = 1; off < 16; off <<= 1) {
                unsigned hi = (unsigned)(best >> 32), lo = (unsigned)best;
                unsigned ho = __shfl_xor(hi, off);
                unsigned lo2 = __shfl_xor(lo, off);
                u64 o = ((u64)ho << 32) | lo2;
                if (o > best) best = o;
            }
            if (ln == 0) {
                int grow = rowBase + wm * 32 + tm * 16 + q * 4 + r;
                if (grow < M_OUT) atomicMax(cells + grow, best);
            }
        }
    }
}

// ================= MID/LOW fallback path =================
__global__ void fill_tables_rm(f16* __restrict__ tbl) {
    long long g = (long long)blockIdx.x * 256 + threadIdx.x;
    if (g >= (long long)(MPAD * 512)) return;
    int m  = (int)(g >> 9);
    int kq = ((int)g & 511) * 8;
    bool valid = (m < M_OUT);
    f16x8 chv, clv, shv, slv;
    for (int j = 0; j < 8; ++j) {
        float c = 0.f, s = 0.f;
        if (valid) {
            int kk = kq + j;
            float ang = CW * (float)(m * kk);
            sincosf(ang, &s, &c);
        }
        f16 h, l;
        split_f16(c, h, l); chv[j] = h; clv[j] = l;
        split_f16(s, h, l); shv[j] = h; slv[j] = l;
    }
    size_t idx = (size_t)m * NDIM + kq;
    *(f16x8*)(tbl + idx)               = chv;
    *(f16x8*)(tbl + A_ELEMS + idx)     = clv;
    *(f16x8*)(tbl + 2 * A_ELEMS + idx) = shv;
    *(f16x8*)(tbl + 3 * A_ELEMS + idx) = slv;
}

#define PK 40   // padded k-stride: all 8 bank groups covered -> 2-way (free)
__global__ __launch_bounds__(256, 2) void dft_gemm_fb(
    const float* __restrict__ x, const float* __restrict__ meanv,
    const f16* __restrict__ tbl, int useTbl,
    u64* __restrict__ cells)
{
    __shared__ alignas(16) f16 Ach[64][PK];
    __shared__ alignas(16) f16 Acl[64][PK];
    __shared__ alignas(16) f16 Ash[64][PK];
    __shared__ alignas(16) f16 Asl[64][PK];
    __shared__ alignas(16) f16 Xh[128][PK];
    __shared__ alignas(16) f16 Xl[128][PK];

    const int t = threadIdx.x;
    const int n0      = blockIdx.x * 128;
    const int rowBase = blockIdx.y * 64;

    const int am  = t >> 2;
    const int akq = (t & 3) * 8;
    const int xn  = t & 127;
    const int xkh = (t >> 7) * 16;

    const int lane = t & 63;
    const int w  = t >> 6;
    const int wm = w >> 1, wn = w & 1;
    const int q  = lane >> 4, ln = lane & 15;

    f32x4 aC0[2][4], aC1[2][4], aS0[2][4], aS1[2][4];
    for (int i = 0; i < 2; ++i)
        for (int j = 0; j < 4; ++j) {
            aC0[i][j] = (f32x4){0.f, 0.f, 0.f, 0.f};
            aC1[i][j] = (f32x4){0.f, 0.f, 0.f, 0.f};
            aS0[i][j] = (f32x4){0.f, 0.f, 0.f, 0.f};
            aS1[i][j] = (f32x4){0.f, 0.f, 0.f, 0.f};
        }

    const int arow = rowBase + am;
    const bool avalid = (arow < M_OUT);

    for (int k0 = 0; k0 < NDIM; k0 += 32) {
        __syncthreads();
        if (useTbl) {
            size_t idx = (size_t)arow * NDIM + k0 + akq;
            *(f16x8*)&Ach[am][akq] = *(const f16x8*)(tbl + idx);
            *(f16x8*)&Acl[am][akq] = *(const f16x8*)(tbl + A_ELEMS + idx);
            *(f16x8*)&Ash[am][akq] = *(const f16x8*)(tbl + 2 * A_ELEMS + idx);
            *(f16x8*)&Asl[am][akq] = *(const f16x8*)(tbl + 3 * A_ELEMS + idx);
        } else {
            f16x8 chv, clv, shv, slv;
            for (int j = 0; j < 8; ++j) {
                float c = 0.f, s = 0.f;
                if (avalid) {
                    int kk = k0 + akq + j;
                    float ang = CW * (float)(arow * kk);
                    sincosf(ang, &s, &c);
                }
                f16 h, l;
                split_f16(c, h, l); chv[j] = h; clv[j] = l;
                split_f16(s, h, l); shv[j] = h; slv[j] = l;
            }
            *(f16x8*)&Ach[am][akq] = chv;
            *(f16x8*)&Acl[am][akq] = clv;
            *(f16x8*)&Ash[am][akq] = shv;
            *(f16x8*)&Asl[am][akq] = slv;
        }
        {
            const float* xp = x + (size_t)(k0 + xkh) * NDIM + n0 + xn;
            f16x8 h0, h1, l0, l1;
            for (int r = 0; r < 16; ++r) {
                float v = xp[(size_t)r * NDIM] - meanv[k0 + xkh + r];
                f16 hi, lo;
                split_f16(v, hi, lo);
                if (r < 8) { h0[r] = hi; l0[r] = lo; }
                else       { h1[r - 8] = hi; l1[r - 8] = lo; }
            }
            *(f16x8*)&Xh[xn][xkh]     = h0;
            *(f16x8*)&Xh[xn][xkh + 8] = h1;
            *(f16x8*)&Xl[xn][xkh]     = l0;
            *(f16x8*)&Xl[xn][xkh + 8] = l1;
        }
        __syncthreads();
        f16x8 fch[2], fcl[2], fsh[2], fsl[2], bh[4], bl[4];
        for (int tm = 0; tm < 2; ++tm) {
            int ml = wm * 32 + tm * 16 + ln;
            fch[tm] = *(const f16x8*)&Ach[ml][q * 8];
            fcl[tm] = *(const f16x8*)&Acl[ml][q * 8];
            fsh[tm] = *(const f16x8*)&Ash[ml][q * 8];
            fsl[tm] = *(const f16x8*)&Asl[ml][q * 8];
        }
        for (int tn = 0; tn < 4; ++tn) {
            int nl = wn * 64 + tn * 16 + ln;
            bh[tn] = *(const f16x8*)&Xh[nl][q * 8];
            bl[tn] = *(const f16x8*)&Xl[nl][q * 8];
        }
        for (int tm = 0; tm < 2; ++tm)
            for (int tn = 0; tn < 4; ++tn) {
                aC0[tm][tn] = __builtin_amdgcn_mfma_f32_16x16x32_f16(fch[tm], bh[tn], aC0[tm][tn], 0, 0, 0);
                aC1[tm][tn] = __builtin_amdgcn_mfma_f32_16x16x32_f16(fch[tm], bl[tn], aC1[tm][tn], 0, 0, 0);
                aC1[tm][tn] = __builtin_amdgcn_mfma_f32_16x16x32_f16(fcl[tm], bh[tn], aC1[tm][tn], 0, 0, 0);
                aS0[tm][tn] = __builtin_amdgcn_mfma_f32_16x16x32_f16(fsh[tm], bh[tn], aS0[tm][tn], 0, 0, 0);
                aS1[tm][tn] = __builtin_amdgcn_mfma_f32_16x16x32_f16(fsh[tm], bl[tn], aS1[tm][tn], 0, 0, 0);
                aS1[tm][tn] = __builtin_amdgcn_mfma_f32_16x16x32_f16(fsl[tm], bh[tn], aS1[tm][tn], 0, 0, 0);
            }
    }

    const float inv64 = 0.015625f;
    for (int tm = 0; tm < 2; ++tm) {
        for (int r = 0; r < 4; ++r) {
            u64 best = 0ull;
            for (int tn = 0; tn < 4; ++tn) {
                float C = aC0[tm][tn][r] + aC1[tm][tn][r] * inv64;
                float S = aS0[tm][tn][r] + aS1[tm][tn][r] * inv64;
                float a2 = C * C + S * S;
                int col = n0 + wn * 64 + tn * 16 + ln;
                u64 key = ((u64)__float_as_uint(a2) << 32) | (unsigned)(~col);
                if (key > best) best = key;
            }
            for (int off = 1; off < 16; off <<= 1) {
                unsigned hi = (unsigned)(best >> 32), lo = (unsigned)best;
                unsigned ho = __shfl_xor(hi, off);
                unsigned lo2 = __shfl_xor(lo, off);
                u64 o = ((u64)ho << 32) | lo2;
                if (o > best) best = o;
            }
            if (ln == 0) {
                int grow = rowBase + wm * 32 + tm * 16 + q * 4 + r;
                if (grow < M_OUT) atomicMax(cells + grow, best);
            }
        }
    }
}

// ---------------- cells -> output ----------------
__global__ void out_kernel(const u64* __restrict__ cells, float* __restrict__ out) {
    int i = blockIdx.x * 256 + threadIdx.x;
    if (i < M_OUT) {
        unsigned col = ~(unsigned)(cells[i] & 0xFFFFFFFFull);
        float freq = (float)col / (4096.0f / 30.0f);
        out[i] = freq * 60.0f;
    }
}

extern "C" void kernel_launch(void* const* d_in, const int* in_sizes, int n_in,
                              void* d_out, int out_size, void* d_ws, size_t ws_size,
                              hipStream_t stream) {
    const float* x = (const float*)d_in[0];
    char* ws = (char*)d_ws;
    float* meanv = (float*)(ws + WS_MEAN);
    u64*   cells = (u64*)(ws + WS_CELLS);
    f16*   atbl  = (f16*)(ws + WS_TBL);
    f16*   xtbl  = (f16*)(ws + WS_XTBL);
    float* out   = (float*)d_out;

    hipLaunchKernelGGL(init_cells, dim3((M_OUT + 255) / 256), dim3(256), 0, stream, cells);
    hipLaunchKernelGGL(mean_kernel, dim3(NDIM), dim3(256), 0, stream, x, meanv);

    if (ws_size >= WS_FULL_END) {
        hipLaunchKernelGGL(fill_A_cm, dim3(512, 9), dim3(256), 0, stream, atbl);
        hipLaunchKernelGGL(fill_X_cm, dim3(512, 16), dim3(256), 0, stream, x, meanv, xtbl);
        hipLaunchKernelGGL(dft_gemm_cm, dim3(32, 33), dim3(256), 0, stream, atbl, xtbl, cells);
    } else if (ws_size >= WS_MID_END) {
        hipLaunchKernelGGL(fill_tables_rm, dim3(4224), dim3(256), 0, stream, atbl);
        hipLaunchKernelGGL(dft_gemm_fb, dim3(32, 33), dim3(256), 0, stream,
                           x, meanv, atbl, 1, cells);
    } else {
        hipLaunchKernelGGL(dft_gemm_fb, dim3(32, 33), dim3(256), 0, stream,
                           x, meanv, atbl, 0, cells);
    }
    hipLaunchKernelGGL(out_kernel, dim3((M_OUT + 255) / 256), dim3(256), 0, stream, cells, out);
}